// Round 2
// baseline (613.327 us; speedup 1.0000x reference)
//
#include <hip/hip_runtime.h>
#include <hip/hip_bf16.h>
#include <math.h>

// Problem constants (reference: B=1024, S=200, D=512, O=512)
#define B_  1024
#define S_  200
#define D_  512
#define O_  512

// ---------------------------------------------------------------------------
// Kernel 1: per-batch sqlen (mask row-sum) + gather last valid row of x.
// ---------------------------------------------------------------------------
__global__ __launch_bounds__(64) void prep_kernel(
    const float* __restrict__ x, const int* __restrict__ mask,
    int* __restrict__ sqlen, float* __restrict__ last)
{
    const int b = blockIdx.x;
    const int lane = threadIdx.x;

    int ssum = 0;
    for (int i = lane; i < S_; i += 64) ssum += mask[b * S_ + i];
#pragma unroll
    for (int off = 32; off; off >>= 1) ssum += __shfl_xor(ssum, off);
    if (lane == 0) sqlen[b] = ssum;

    // gather x[b, sqlen-1, :] -> last[b, :]   (512 floats, 8 per lane)
    const float* row = x + ((size_t)b * S_ + (ssum - 1)) * D_;
    float4 v0 = *(const float4*)(row + lane * 8);
    float4 v1 = *(const float4*)(row + lane * 8 + 4);
    *(float4*)(last + (size_t)b * D_ + lane * 8)     = v0;
    *(float4*)(last + (size_t)b * D_ + lane * 8 + 4) = v1;
}

// ---------------------------------------------------------------------------
// Kernel 2/3/5: fp32 tiled GEMM.  C[M,N] = A[M,K] * op(B) (+bias) (tanh)
//   TB=true : B is [N,K], use B^T  (for q = last @ Wq^T, out = ctx @ Wv^T)
//   TB=false: B is [K,N]           (for qk = q @ Wk)
// BM=BN=64, BK=16, 256 threads, 4x4 micro-tile per thread.
// M=1024, N=512, K=512 are all divisible by tile dims -> no bounds checks.
// ---------------------------------------------------------------------------
template<bool TB, bool BIAS, bool TANH>
__global__ __launch_bounds__(256) void gemm_kernel(
    const float* __restrict__ A, const float* __restrict__ Bm,
    const float* __restrict__ bias, float* __restrict__ C,
    int M, int N, int K)
{
    constexpr int BM = 64, BN = 64, BK = 16;
    __shared__ float As[BK][BM + 4];   // +4 pad keeps float4 alignment, kills conflicts
    __shared__ float Bs[BK][BN + 4];

    const int tid = threadIdx.x;
    const int tx = tid & 15;          // output col group (4 cols)
    const int ty = tid >> 4;          // output row group (4 rows)
    const int m0 = blockIdx.x * BM;
    const int n0 = blockIdx.y * BN;

    // staging-load mapping: one float4 per thread
    const int ar = tid >> 2;          // 0..63  (row within 64-row tile)
    const int ac = (tid & 3) << 2;    // 0,4,8,12 (k offset)

    float acc[4][4] = {};

    for (int k0 = 0; k0 < K; k0 += BK) {
        float4 av = *(const float4*)(A + (size_t)(m0 + ar) * K + k0 + ac);
        float4 bv;
        if (TB) {
            bv = *(const float4*)(Bm + (size_t)(n0 + ar) * K + k0 + ac);
        } else {
            bv = *(const float4*)(Bm + (size_t)(k0 + (tid >> 4)) * N + n0 + ((tid & 15) << 2));
        }
        __syncthreads();   // previous iteration's LDS reads done
        As[ac + 0][ar] = av.x; As[ac + 1][ar] = av.y;
        As[ac + 2][ar] = av.z; As[ac + 3][ar] = av.w;
        if (TB) {
            Bs[ac + 0][ar] = bv.x; Bs[ac + 1][ar] = bv.y;
            Bs[ac + 2][ar] = bv.z; Bs[ac + 3][ar] = bv.w;
        } else {
            *(float4*)&Bs[tid >> 4][(tid & 15) << 2] = bv;
        }
        __syncthreads();

#pragma unroll
        for (int kk = 0; kk < BK; ++kk) {
            float4 a4 = *(const float4*)&As[kk][ty << 2];
            float4 b4 = *(const float4*)&Bs[kk][tx << 2];
            float aa[4] = {a4.x, a4.y, a4.z, a4.w};
            float bb[4] = {b4.x, b4.y, b4.z, b4.w};
#pragma unroll
            for (int i = 0; i < 4; ++i)
#pragma unroll
                for (int j = 0; j < 4; ++j)
                    acc[i][j] = fmaf(aa[i], bb[j], acc[i][j]);
        }
    }

#pragma unroll
    for (int i = 0; i < 4; ++i) {
        float o[4];
#pragma unroll
        for (int j = 0; j < 4; ++j) {
            float v = acc[i][j];
            if (BIAS) v += bias[n0 + (tx << 2) + j];
            if (TANH) v = tanhf(v);
            o[j] = v;
        }
        float4 ov = make_float4(o[0], o[1], o[2], o[3]);
        *(float4*)(C + (size_t)(m0 + (ty << 2) + i) * N + n0 + (tx << 2)) = ov;
    }
}

// ---------------------------------------------------------------------------
// Kernel 4: fused masked attention over x directly.
//   scores[s] = x[b,s,:] . qk[b,:]          (softmax shift-invariance: q.bk dropped)
//   ctx[b,:]  = sum_s softmax(scores)[s] * x[b,s,:]
// One block per b (4 waves). Each wave: independent online softmax over rows
// s = wave, wave+4, ...  (m, l, 8-elem ctx partial per lane), merged in LDS.
// ---------------------------------------------------------------------------
__global__ __launch_bounds__(256) void attn_kernel(
    const float* __restrict__ x, const float* __restrict__ qk,
    const int* __restrict__ sqlen, float* __restrict__ ctx)
{
    const int b    = blockIdx.x;
    const int tid  = threadIdx.x;
    const int wave = tid >> 6;
    const int lane = tid & 63;
    const int L    = sqlen[b] - 1;           // #valid keys, >= 1

    // per-lane slice of qk[b]: elements lane*8 .. lane*8+7
    const float* qkb = qk + (size_t)b * D_ + lane * 8;
    const float4 q0 = *(const float4*)qkb;
    const float4 q1 = *(const float4*)(qkb + 4);

    float m = -INFINITY, l = 0.f;
    float acc[8] = {0.f, 0.f, 0.f, 0.f, 0.f, 0.f, 0.f, 0.f};

    int s = wave;
    if (s < L) {
        const float* base = x + (size_t)b * S_ * D_ + lane * 8;
        float4 c0 = *(const float4*)(base + (size_t)s * D_);
        float4 c1 = *(const float4*)(base + (size_t)s * D_ + 4);
        for (;;) {
            const int  sn   = s + 4;
            const bool more = sn < L;
            const int  sp   = more ? sn : s;      // clamped prefetch (stays in range)
            float4 n0 = *(const float4*)(base + (size_t)sp * D_);
            float4 n1 = *(const float4*)(base + (size_t)sp * D_ + 4);

            // dot(x_row, qk) : per-lane partial then 64-lane butterfly
            float p = c0.x * q0.x + c0.y * q0.y + c0.z * q0.z + c0.w * q0.w
                    + c1.x * q1.x + c1.y * q1.y + c1.z * q1.z + c1.w * q1.w;
#pragma unroll
            for (int off = 32; off; off >>= 1) p += __shfl_xor(p, off);

            const float mn = fmaxf(m, p);
            const float r  = __expf(m - mn);   // m=-inf first iter -> r=0
            const float e  = __expf(p - mn);
            l = l * r + e;
            acc[0] = acc[0] * r + e * c0.x;
            acc[1] = acc[1] * r + e * c0.y;
            acc[2] = acc[2] * r + e * c0.z;
            acc[3] = acc[3] * r + e * c0.w;
            acc[4] = acc[4] * r + e * c1.x;
            acc[5] = acc[5] * r + e * c1.y;
            acc[6] = acc[6] * r + e * c1.z;
            acc[7] = acc[7] * r + e * c1.w;
            m = mn;

            if (!more) break;
            s = sn; c0 = n0; c1 = n1;
        }
    }

    // merge 4 per-wave online-softmax states (flash-style combine)
    __shared__ float s_m[4], s_l[4];
    __shared__ float s_ctx[4][D_];
    if (lane == 0) { s_m[wave] = m; s_l[wave] = l; }
#pragma unroll
    for (int j = 0; j < 8; ++j) s_ctx[wave][lane * 8 + j] = acc[j];
    __syncthreads();

    const float M4 = fmaxf(fmaxf(s_m[0], s_m[1]), fmaxf(s_m[2], s_m[3]));
    const float sc0 = __expf(s_m[0] - M4);   // empty wave: -inf -> 0
    const float sc1 = __expf(s_m[1] - M4);
    const float sc2 = __expf(s_m[2] - M4);
    const float sc3 = __expf(s_m[3] - M4);
    const float lt  = s_l[0] * sc0 + s_l[1] * sc1 + s_l[2] * sc2 + s_l[3] * sc3;
    const float inv = 1.f / lt;

    const int d = tid * 2;
    float v0 = (s_ctx[0][d]     * sc0 + s_ctx[1][d]     * sc1 +
                s_ctx[2][d]     * sc2 + s_ctx[3][d]     * sc3) * inv;
    float v1 = (s_ctx[0][d + 1] * sc0 + s_ctx[1][d + 1] * sc1 +
                s_ctx[2][d + 1] * sc2 + s_ctx[3][d + 1] * sc3) * inv;
    float2 ov = make_float2(v0, v1);
    *(float2*)(ctx + (size_t)b * D_ + d) = ov;
}

// ---------------------------------------------------------------------------
// Orchestration.
// Workspace (ping-pong, ~4.2 MB):
//   sqlen int[1024] (4 KB) | buf0 [1024x512] f32 (2 MB) | buf1 [1024x512] f32 (2 MB)
// Live ranges: buf0 = last, then qk.  buf1 = q, then ctx.
//   prep:  x,mask          -> sqlen, buf0(last)
//   gemm1: buf0(last)      -> buf1(q)
//   gemm2: buf1(q)         -> buf0(qk)
//   attn:  x, buf0(qk)     -> buf1(ctx)
//   gemm3: buf1(ctx)       -> out
// ---------------------------------------------------------------------------
extern "C" void kernel_launch(void* const* d_in, const int* in_sizes, int n_in,
                              void* d_out, int out_size, void* d_ws, size_t ws_size,
                              hipStream_t stream)
{
    const float* x    = (const float*)d_in[0];
    const int*   mask = (const int*)  d_in[1];
    const float* Wq_w = (const float*)d_in[2];
    const float* Wq_b = (const float*)d_in[3];
    const float* Wk_w = (const float*)d_in[4];
    const float* Wk_b = (const float*)d_in[5];   // unused: softmax shift invariance
    const float* Wv_w = (const float*)d_in[6];
    const float* Wv_b = (const float*)d_in[7];
    (void)Wk_b; (void)in_sizes; (void)n_in; (void)out_size; (void)ws_size;
    float* out = (float*)d_out;

    char* ws = (char*)d_ws;
    int*   sqlen = (int*)ws;                              // 4 KB
    float* buf0  = (float*)(ws + 4096);                   // 2 MB
    float* buf1  = (float*)(ws + 4096 + (1u << 21));      // 2 MB

    float* last = buf0;
    float* q    = buf1;
    float* qk   = buf0;   // overwrites last (dead after gemm1)
    float* ctx  = buf1;   // overwrites q    (dead after gemm2)

    prep_kernel<<<B_, 64, 0, stream>>>(x, mask, sqlen, last);

    dim3 g(B_ / 64, O_ / 64);   // (16, 8)
    // q = last @ Wq_w^T + Wq_b
    gemm_kernel<true,  true,  false><<<g, 256, 0, stream>>>(last, Wq_w, Wq_b, q,  B_, O_, D_);
    // qk = q @ Wk_w   (qk[b,d] = sum_o q[b,o] * Wk_w[o,d]) ; K-bias dropped (shift-invariant)
    gemm_kernel<false, false, false><<<g, 256, 0, stream>>>(q,    Wk_w, nullptr, qk, B_, D_, O_);
    // fused masked softmax-attention over x -> ctx
    attn_kernel<<<B_, 256, 0, stream>>>(x, qk, sqlen, ctx);
    // out = tanh(ctx @ Wv_w^T + Wv_b)
    gemm_kernel<true,  true,  true ><<<g, 256, 0, stream>>>(ctx,  Wv_w, Wv_b, out, B_, O_, D_);
}

// Round 4
// 592.359 us; speedup vs baseline: 1.0354x; 1.0354x over previous
//
#include <hip/hip_runtime.h>
#include <hip/hip_bf16.h>
#include <math.h>

// Problem constants (reference: B=1024, S=200, D=512, O=512)
#define B_  1024
#define S_  200
#define D_  512
#define O_  512

// ---------------------------------------------------------------------------
// Kernel 1: per-batch sqlen (mask row-sum) + gather last valid row of x.
// ---------------------------------------------------------------------------
__global__ __launch_bounds__(64) void prep_kernel(
    const float* __restrict__ x, const int* __restrict__ mask,
    int* __restrict__ sqlen, float* __restrict__ last)
{
    const int b = blockIdx.x;
    const int lane = threadIdx.x;

    int ssum = 0;
    for (int i = lane; i < S_; i += 64) ssum += mask[b * S_ + i];
#pragma unroll
    for (int off = 32; off; off >>= 1) ssum += __shfl_xor(ssum, off);

    if (lane == 0) sqlen[b] = ssum;

    // gather x[b, sqlen-1, :] -> last[b, :]   (512 floats, 8 per lane)
    const float* row = x + ((size_t)b * S_ + (ssum - 1)) * D_;
    float4 v0 = *(const float4*)(row + lane * 8);
    float4 v1 = *(const float4*)(row + lane * 8 + 4);
    *(float4*)(last + (size_t)b * D_ + lane * 8)     = v0;
    *(float4*)(last + (size_t)b * D_ + lane * 8 + 4) = v1;
}

// ---------------------------------------------------------------------------
// gemm16: fp32 GEMM, 16x16 output tile per 1-wave (64-thread) block, BK=32.
//   AMODE 0: A is [M][K] row-major (lda=K)   -> transposed stage into As[k][m]
//   AMODE 1: A is [K][M] row-major (lda=M)   -> direct stage
//   BMODE 0: B is [N][K] row-major (ldb=K)   -> C += A * B^T
//   BMODE 1: B is [K][N] row-major (ldb=N)   -> C += A * B
//   BIASOUT: blocks with blockIdx.x==0 also emit cvec[n] = sum_k bfold[k]*Bs[k][n]
//   BIAS:    C += bias[n];  TANH: C = tanh(C)
// Grid: (M/16, N/16). High block count -> 8 blocks/CU, 2 waves/SIMD.
// Micro-tile 2x2 per lane: lane = ly*8+lx, rows 2ly..2ly+1, cols 2lx..2lx+1.
// LDS strides: 'R' stage = 22 (breaks 4-way write conflict), 'K' stage = 20
// (keeps 16B alignment for float4 writes). Inner float2 reads are 8B aligned
// and 8-address broadcast (conflict-free) in both cases.
// ---------------------------------------------------------------------------
template<int AMODE, int BMODE, bool BIASOUT, bool BIAS, bool TANH>
__global__ __launch_bounds__(64) void gemm16(
    const float* __restrict__ A, const float* __restrict__ Bm,
    const float* __restrict__ bias, float* __restrict__ C,
    float* __restrict__ cvec, const float* __restrict__ bfold,
    int M, int N, int K, int lda, int ldb)
{
    constexpr int SA = (AMODE == 0) ? 22 : 20;
    constexpr int SB = (BMODE == 0) ? 22 : 20;
    __shared__ float As[32 * SA];
    __shared__ float Bs[32 * SB];
    __shared__ float sBq[32];

    const int lane = threadIdx.x;
    const int m0 = blockIdx.x * 16;
    const int n0 = blockIdx.y * 16;
    const int ly = lane >> 3;      // 0..7
    const int lx = lane & 7;       // 0..7

    float a00 = 0.f, a01 = 0.f, a10 = 0.f, a11 = 0.f;
    float cb0 = 0.f, cb1 = 0.f;

    for (int k0 = 0; k0 < K; k0 += 32) {
        float4 av0, av1, bv0, bv1;
        if (AMODE == 0) {
            const float* p = A + (size_t)(m0 + (lane >> 2)) * lda + k0 + ((lane & 3) << 3);
            av0 = *(const float4*)p;  av1 = *(const float4*)(p + 4);
        } else {
            const float* p = A + (size_t)(k0 + (lane >> 1)) * lda + m0 + ((lane & 1) << 3);
            av0 = *(const float4*)p;  av1 = *(const float4*)(p + 4);
        }
        if (BMODE == 0) {
            const float* p = Bm + (size_t)(n0 + (lane >> 2)) * ldb + k0 + ((lane & 3) << 3);
            bv0 = *(const float4*)p;  bv1 = *(const float4*)(p + 4);
        } else {
            const float* p = Bm + (size_t)(k0 + (lane >> 1)) * ldb + n0 + ((lane & 1) << 3);
            bv0 = *(const float4*)p;  bv1 = *(const float4*)(p + 4);
        }
        float bqv = 0.f;
        if (BIASOUT) bqv = bfold[k0 + (lane & 31)];

        __syncthreads();   // previous iteration's LDS reads done (1 wave: cheap)

        if (AMODE == 0) {
            const int mr = lane >> 2, kc = (lane & 3) << 3;
            As[(kc + 0) * SA + mr] = av0.x; As[(kc + 1) * SA + mr] = av0.y;
            As[(kc + 2) * SA + mr] = av0.z; As[(kc + 3) * SA + mr] = av0.w;
            As[(kc + 4) * SA + mr] = av1.x; As[(kc + 5) * SA + mr] = av1.y;
            As[(kc + 6) * SA + mr] = av1.z; As[(kc + 7) * SA + mr] = av1.w;
        } else {
            const int kr = lane >> 1, mc = (lane & 1) << 3;
            *(float4*)&As[kr * SA + mc]     = av0;
            *(float4*)&As[kr * SA + mc + 4] = av1;
        }
        if (BMODE == 0) {
            const int nr = lane >> 2, kc = (lane & 3) << 3;
            Bs[(kc + 0) * SB + nr] = bv0.x; Bs[(kc + 1) * SB + nr] = bv0.y;
            Bs[(kc + 2) * SB + nr] = bv0.z; Bs[(kc + 3) * SB + nr] = bv0.w;
            Bs[(kc + 4) * SB + nr] = bv1.x; Bs[(kc + 5) * SB + nr] = bv1.y;
            Bs[(kc + 6) * SB + nr] = bv1.z; Bs[(kc + 7) * SB + nr] = bv1.w;
        } else {
            const int kr = lane >> 1, nc = (lane & 1) << 3;
            *(float4*)&Bs[kr * SB + nc]     = bv0;
            *(float4*)&Bs[kr * SB + nc + 4] = bv1;
        }
        if (BIASOUT && lane < 32) sBq[lane] = bqv;

        __syncthreads();

#pragma unroll
        for (int kk = 0; kk < 32; ++kk) {
            float2 a = *(const float2*)&As[kk * SA + (ly << 1)];
            float2 b = *(const float2*)&Bs[kk * SB + (lx << 1)];
            a00 = fmaf(a.x, b.x, a00); a01 = fmaf(a.x, b.y, a01);
            a10 = fmaf(a.y, b.x, a10); a11 = fmaf(a.y, b.y, a11);
            if (BIASOUT) {
                float qv = sBq[kk];
                cb0 = fmaf(qv, b.x, cb0); cb1 = fmaf(qv, b.y, cb1);
            }
        }
    }

    const int r0 = m0 + (ly << 1);
    const int c0 = n0 + (lx << 1);
    float o00 = a00, o01 = a01, o10 = a10, o11 = a11;
    if (BIAS) {
        float b0 = bias[c0], b1 = bias[c0 + 1];
        o00 += b0; o01 += b1; o10 += b0; o11 += b1;
    }
    if (TANH) { o00 = tanhf(o00); o01 = tanhf(o01); o10 = tanhf(o10); o11 = tanhf(o11); }
    *(float2*)(C + (size_t)r0 * N + c0)       = make_float2(o00, o01);
    *(float2*)(C + (size_t)(r0 + 1) * N + c0) = make_float2(o10, o11);

    if (BIASOUT && blockIdx.x == 0 && ly == 0)
        *(float2*)(cvec + c0) = make_float2(cb0, cb1);
}

// ---------------------------------------------------------------------------
// attn: fused masked attention over x directly.
//   scores[s] = x[b,s,:] . qk[b,:]      (q.bk dropped: softmax shift-invariant)
//   ctx[b,:]  = sum_s softmax(scores)[s] * x[b,s,:]
// One block per b, 4 waves; wave w owns row-pairs {2w, 2w+1} + t*8.
// 2 rows per iteration halves the serial online-softmax chain. Next pair is
// prefetched (clamped) before the reduce. 4 per-wave states merged in LDS.
// ---------------------------------------------------------------------------
__global__ __launch_bounds__(256) void attn_kernel(
    const float* __restrict__ x, const float* __restrict__ qk,
    const int* __restrict__ sqlen, float* __restrict__ ctx)
{
    const int b    = blockIdx.x;
    const int tid  = threadIdx.x;
    const int w    = tid >> 6;
    const int lane = tid & 63;
    const int L    = sqlen[b] - 1;           // #valid keys, >= 1

    const float* qkb = qk + (size_t)b * D_ + lane * 8;
    const float4 q0 = *(const float4*)qkb;
    const float4 q1 = *(const float4*)(qkb + 4);

    float m = -INFINITY, l = 0.f;
    float acc[8] = {0.f, 0.f, 0.f, 0.f, 0.f, 0.f, 0.f, 0.f};

    int s0 = w * 2;
    if (s0 < L) {
        const float* base = x + (size_t)b * S_ * D_ + lane * 8;
        const int s1c = (s0 + 1 < L) ? s0 + 1 : s0;
        float4 c0 = *(const float4*)(base + (size_t)s0  * D_);
        float4 c1 = *(const float4*)(base + (size_t)s0  * D_ + 4);
        float4 c2 = *(const float4*)(base + (size_t)s1c * D_);
        float4 c3 = *(const float4*)(base + (size_t)s1c * D_ + 4);
        for (;;) {
            const int  sn   = s0 + 8;
            const bool more = sn < L;
            const int  sp0  = more ? sn : s0;
            const int  sp1  = (sn + 1 < L) ? sn + 1 : sp0;
            float4 n0 = *(const float4*)(base + (size_t)sp0 * D_);
            float4 n1 = *(const float4*)(base + (size_t)sp0 * D_ + 4);
            float4 n2 = *(const float4*)(base + (size_t)sp1 * D_);
            float4 n3 = *(const float4*)(base + (size_t)sp1 * D_ + 4);

            float p0 = c0.x*q0.x + c0.y*q0.y + c0.z*q0.z + c0.w*q0.w
                     + c1.x*q1.x + c1.y*q1.y + c1.z*q1.z + c1.w*q1.w;
            float p1 = c2.x*q0.x + c2.y*q0.y + c2.z*q0.z + c2.w*q0.w
                     + c3.x*q1.x + c3.y*q1.y + c3.z*q1.z + c3.w*q1.w;
#pragma unroll
            for (int off = 32; off; off >>= 1) {
                p0 += __shfl_xor(p0, off);
                p1 += __shfl_xor(p1, off);
            }
            if (s0 + 1 >= L) p1 = -INFINITY;   // second row of pair invalid

            const float mn = fmaxf(m, fmaxf(p0, p1));
            const float r  = __expf(m  - mn);   // m=-inf first iter -> 0
            const float e0 = __expf(p0 - mn);
            const float e1 = __expf(p1 - mn);   // p1=-inf -> 0
            l = l * r + e0 + e1;
            acc[0] = acc[0]*r + e0*c0.x + e1*c2.x;
            acc[1] = acc[1]*r + e0*c0.y + e1*c2.y;
            acc[2] = acc[2]*r + e0*c0.z + e1*c2.z;
            acc[3] = acc[3]*r + e0*c0.w + e1*c2.w;
            acc[4] = acc[4]*r + e0*c1.x + e1*c3.x;
            acc[5] = acc[5]*r + e0*c1.y + e1*c3.y;
            acc[6] = acc[6]*r + e0*c1.z + e1*c3.z;
            acc[7] = acc[7]*r + e0*c1.w + e1*c3.w;
            m = mn;

            if (!more) break;
            s0 = sn; c0 = n0; c1 = n1; c2 = n2; c3 = n3;
        }
    }

    // merge 4 per-wave online-softmax states (flash-style combine)
    __shared__ float s_m[4], s_l[4];
    __shared__ float s_ctx[4][D_];
    if (lane == 0) { s_m[w] = m; s_l[w] = l; }
#pragma unroll
    for (int j = 0; j < 8; ++j) s_ctx[w][lane * 8 + j] = acc[j];
    __syncthreads();

    const float M4 = fmaxf(fmaxf(s_m[0], s_m[1]), fmaxf(s_m[2], s_m[3]));
    const float sc0 = __expf(s_m[0] - M4);   // empty wave: -inf -> 0
    const float sc1 = __expf(s_m[1] - M4);
    const float sc2 = __expf(s_m[2] - M4);
    const float sc3 = __expf(s_m[3] - M4);
    const float lt  = s_l[0]*sc0 + s_l[1]*sc1 + s_l[2]*sc2 + s_l[3]*sc3;
    const float inv = 1.f / lt;

    const int d = tid * 2;
    float v0 = (s_ctx[0][d]     * sc0 + s_ctx[1][d]     * sc1 +
                s_ctx[2][d]     * sc2 + s_ctx[3][d]     * sc3) * inv;
    float v1 = (s_ctx[0][d + 1] * sc0 + s_ctx[1][d + 1] * sc1 +
                s_ctx[2][d + 1] * sc2 + s_ctx[3][d + 1] * sc3) * inv;
    *(float2*)(ctx + (size_t)b * D_ + d) = make_float2(v0, v1);
}

// ---------------------------------------------------------------------------
// Orchestration.
//   qk[b] = Wk^T(Wq last_b + bq) = Wqk^T last_b + c,  Wqk = Wq^T Wk (512x512),
//   c = Wk^T bq  -> folds old GEMM1+GEMM2 into one 512-row GEMM + one 1024-row
//   GEMM (and c comes free out of the Wqk kernel).
// ws: sqlen int[1024] | c f32[512] | Wqk f32[512x512] | last | qk | ctx
// ---------------------------------------------------------------------------
extern "C" void kernel_launch(void* const* d_in, const int* in_sizes, int n_in,
                              void* d_out, int out_size, void* d_ws, size_t ws_size,
                              hipStream_t stream)
{
    const float* x    = (const float*)d_in[0];
    const int*   mask = (const int*)  d_in[1];
    const float* Wq_w = (const float*)d_in[2];
    const float* Wq_b = (const float*)d_in[3];
    const float* Wk_w = (const float*)d_in[4];
    const float* Wk_b = (const float*)d_in[5];   // unused: softmax shift invariance
    const float* Wv_w = (const float*)d_in[6];
    const float* Wv_b = (const float*)d_in[7];
    (void)Wk_b; (void)in_sizes; (void)n_in; (void)out_size; (void)ws_size;
    float* out = (float*)d_out;

    char* ws = (char*)d_ws;
    int*   sqlen = (int*)ws;                                   // 4 KB
    float* cvec  = (float*)(ws + 4096);                        // 4 KB slot
    float* Wqk   = (float*)(ws + 8192);                        // 1 MB
    float* last  = (float*)(ws + 8192 + (1u << 20));           // 2 MB
    float* qk    = last + (size_t)B_ * D_;                     // 2 MB
    float* ctxb  = qk   + (size_t)B_ * D_;                     // 2 MB

    // Wqk = Wq^T @ Wk  (+ cvec = Wk^T @ Wq_b from the blockIdx.x==0 row)
    gemm16<1, 1, true, false, false><<<dim3(32, 32), 64, 0, stream>>>(
        Wq_w, Wk_w, nullptr, Wqk, cvec, Wq_b, D_, D_, O_, D_, D_);

    prep_kernel<<<B_, 64, 0, stream>>>(x, mask, sqlen, last);

    // qk = last @ Wqk + c
    gemm16<0, 1, false, true, false><<<dim3(B_ / 16, D_ / 16), 64, 0, stream>>>(
        last, Wqk, cvec, qk, nullptr, nullptr, B_, D_, D_, D_, D_);

    attn_kernel<<<B_, 256, 0, stream>>>(x, qk, sqlen, ctxb);

    // out = tanh(ctx @ Wv^T + bv)
    gemm16<0, 0, false, true, true><<<dim3(B_ / 16, O_ / 16), 64, 0, stream>>>(
        ctxb, Wv_w, Wv_b, out, nullptr, nullptr, B_, O_, D_, D_, D_);
}